// Round 1
// baseline (683.421 us; speedup 1.0000x reference)
//
#include <hip/hip_runtime.h>
#include <hip/hip_bf16.h>
#include <math.h>

#define N_TOK 4096
#define IN_CH 256
#define OUT_CH 64
#define HEADS 8
#define PROJ (OUT_CH * HEADS) /* 512 */

// ---------------------------------------------------------------------------
// Kernel 1: Q/K/V projections.  C[m][n] = sum_k X[m][k] * W[n][k] + b[n]
// grid (PROJ/64, N/64, 3), block 256.  64x64 output tile, 4x4 per thread.
// LDS tiles stored k-major ([k][m], [k][n], pad 4) so the inner loop is
// 2x ds_read_b128 per 16 FMA, conflict-free reads.
// ---------------------------------------------------------------------------
__global__ __launch_bounds__(256) void proj_kernel(
    const float* __restrict__ X,
    const float* __restrict__ Wq, const float* __restrict__ bq,
    const float* __restrict__ Wk, const float* __restrict__ bk,
    const float* __restrict__ Wv, const float* __restrict__ bv,
    float* __restrict__ Qo, float* __restrict__ Ko, float* __restrict__ Vo)
{
    const int z = blockIdx.z;
    const float* W    = (z == 0) ? Wq : (z == 1) ? Wk : Wv;
    const float* bias = (z == 0) ? bq : (z == 1) ? bk : bv;
    float* out        = (z == 0) ? Qo : (z == 1) ? Ko : Vo;

    const int c0 = blockIdx.x * 64;  // proj-dim tile
    const int n0 = blockIdx.y * 64;  // token tile

    __shared__ float Xs[64 * 68];  // [k][m]
    __shared__ float Ws[64 * 68];  // [k][n]

    const int tid = threadIdx.x;
    const int tx = tid & 15, ty = tid >> 4;
    const int lc = tid & 15, lr = tid >> 4;

    float acc[4][4] = {};

    for (int kt = 0; kt < IN_CH / 64; ++kt) {
        const int k0 = kt * 64;
        __syncthreads();
#pragma unroll
        for (int r = 0; r < 4; ++r) {
            const int row = lr + r * 16;
            float4 f = *(const float4*)&X[(size_t)(n0 + row) * IN_CH + k0 + 4 * lc];
            Xs[(4 * lc + 0) * 68 + row] = f.x;
            Xs[(4 * lc + 1) * 68 + row] = f.y;
            Xs[(4 * lc + 2) * 68 + row] = f.z;
            Xs[(4 * lc + 3) * 68 + row] = f.w;
            float4 g = *(const float4*)&W[(size_t)(c0 + row) * IN_CH + k0 + 4 * lc];
            Ws[(4 * lc + 0) * 68 + row] = g.x;
            Ws[(4 * lc + 1) * 68 + row] = g.y;
            Ws[(4 * lc + 2) * 68 + row] = g.z;
            Ws[(4 * lc + 3) * 68 + row] = g.w;
        }
        __syncthreads();
#pragma unroll 8
        for (int k = 0; k < 64; ++k) {
            float4 a = *(const float4*)&Xs[k * 68 + 4 * ty];
            float4 b = *(const float4*)&Ws[k * 68 + 4 * tx];
            float av[4] = {a.x, a.y, a.z, a.w};
            float bv4[4] = {b.x, b.y, b.z, b.w};
#pragma unroll
            for (int i = 0; i < 4; ++i)
#pragma unroll
                for (int j = 0; j < 4; ++j)
                    acc[i][j] = fmaf(av[i], bv4[j], acc[i][j]);
        }
    }

    float4 bb = *(const float4*)&bias[c0 + 4 * tx];
    float bbv[4] = {bb.x, bb.y, bb.z, bb.w};
#pragma unroll
    for (int i = 0; i < 4; ++i) {
        float4 o;
        o.x = acc[i][0] + bbv[0];
        o.y = acc[i][1] + bbv[1];
        o.z = acc[i][2] + bbv[2];
        o.w = acc[i][3] + bbv[3];
        *(float4*)&out[(size_t)(n0 + 4 * ty + i) * PROJ + c0 + 4 * tx] = o;
    }
}

// ---------------------------------------------------------------------------
// Kernel 2: fused sigmoid attention, flash-style (no max needed: sigmoid is
// bounded; denominators are positive sums).
// grid (N/64, HEADS), block 256.  Per block: 64 queries x one head.
// Per key tile: S_T[l][m] = sigmoid(K.Q^T) written transposed to LDS so the
// PV phase reads both P and V as conflict-free ds_read_b128 along l.
// Accumulates unnormalized num[64q][64d] in registers, den[64q] via
// registers + shfl + LDS reduce.  Normalization deferred to kernel 3.
// ---------------------------------------------------------------------------
__global__ __launch_bounds__(256) void attn_kernel(
    const float* __restrict__ Q, const float* __restrict__ K,
    const float* __restrict__ V,
    float* __restrict__ NUM, float* __restrict__ DEN)
{
    const int h = blockIdx.y;
    const int n0 = blockIdx.x * 64;

    __shared__ float Qs[64 * 68];   // [k][m]
    __shared__ float Ks[64 * 68];   // [k][l]
    __shared__ float Vs[64 * 68];   // [l][d]
    __shared__ float Ss[64 * 68];   // [l][m]  (sigmoid probs, transposed)
    __shared__ float den_s[256];

    const int tid = threadIdx.x;
    const int tx = tid & 15, ty = tid >> 4;
    const int lc = tid & 15, lr = tid >> 4;
    const int wave = tid >> 6;

    // stage Q tile transposed once: Qs[k][m]
#pragma unroll
    for (int r = 0; r < 4; ++r) {
        const int row = lr + r * 16;
        float4 f = *(const float4*)&Q[(size_t)(n0 + row) * PROJ + h * 64 + 4 * lc];
        Qs[(4 * lc + 0) * 68 + row] = f.x;
        Qs[(4 * lc + 1) * 68 + row] = f.y;
        Qs[(4 * lc + 2) * 68 + row] = f.z;
        Qs[(4 * lc + 3) * 68 + row] = f.w;
    }

    float nacc[4][4] = {};
    float dacc[4] = {};

    for (int lt = 0; lt < N_TOK / 64; ++lt) {
        const int l0 = lt * 64;
        __syncthreads();  // previous phase-2 done reading Vs/Ss (and Qs visible on iter 0)
#pragma unroll
        for (int r = 0; r < 4; ++r) {
            const int row = lr + r * 16;
            float4 f = *(const float4*)&K[(size_t)(l0 + row) * PROJ + h * 64 + 4 * lc];
            Ks[(4 * lc + 0) * 68 + row] = f.x;
            Ks[(4 * lc + 1) * 68 + row] = f.y;
            Ks[(4 * lc + 2) * 68 + row] = f.z;
            Ks[(4 * lc + 3) * 68 + row] = f.w;
            float4 g = *(const float4*)&V[(size_t)(l0 + row) * PROJ + h * 64 + 4 * lc];
            *(float4*)&Vs[row * 68 + 4 * lc] = g;
        }
        __syncthreads();

        // phase 1: s[i][j] = sum_k K[l0+4ty+i][k] * Q[n0+4tx+j][k]
        float s[4][4] = {};
#pragma unroll 8
        for (int k = 0; k < 64; ++k) {
            float4 a = *(const float4*)&Ks[k * 68 + 4 * ty];
            float4 b = *(const float4*)&Qs[k * 68 + 4 * tx];
            float av[4] = {a.x, a.y, a.z, a.w};
            float bv4[4] = {b.x, b.y, b.z, b.w};
#pragma unroll
            for (int i = 0; i < 4; ++i)
#pragma unroll
                for (int j = 0; j < 4; ++j)
                    s[i][j] = fmaf(av[i], bv4[j], s[i][j]);
        }
        // sigmoid; den partial (den[m=4tx+j]); write transposed probs Ss[l][m]
#pragma unroll
        for (int i = 0; i < 4; ++i)
#pragma unroll
            for (int j = 0; j < 4; ++j) {
                float p = 1.0f / (1.0f + __expf(-s[i][j]));
                dacc[j] += p;
                Ss[(4 * ty + i) * 68 + 4 * tx + j] = p;
            }
        __syncthreads();

        // phase 2: num[m=4ty+i][d=4tx+j] += sum_l P[l][m] * V[l][d]
#pragma unroll 8
        for (int l = 0; l < 64; ++l) {
            float4 a = *(const float4*)&Ss[l * 68 + 4 * ty];
            float4 b = *(const float4*)&Vs[l * 68 + 4 * tx];
            float av[4] = {a.x, a.y, a.z, a.w};
            float bv4[4] = {b.x, b.y, b.z, b.w};
#pragma unroll
            for (int i = 0; i < 4; ++i)
#pragma unroll
                for (int j = 0; j < 4; ++j)
                    nacc[i][j] = fmaf(av[i], bv4[j], nacc[i][j]);
        }
    }

    // epilogue: unnormalized numerator
#pragma unroll
    for (int i = 0; i < 4; ++i) {
        float4 o;
        o.x = nacc[i][0];
        o.y = nacc[i][1];
        o.z = nacc[i][2];
        o.w = nacc[i][3];
        *(float4*)&NUM[(size_t)(n0 + 4 * ty + i) * PROJ + h * 64 + 4 * tx] = o;
    }

    // denominator: reduce dacc[j] over ty (shfl within wave) then across waves
    float dred[4];
#pragma unroll
    for (int j = 0; j < 4; ++j) {
        float v = dacc[j];
        v += __shfl_xor(v, 16);
        v += __shfl_xor(v, 32);
        dred[j] = v;
    }
    if ((tid & 63) < 16) {
#pragma unroll
        for (int j = 0; j < 4; ++j)
            den_s[wave * 64 + 4 * (tid & 15) + j] = dred[j];
    }
    __syncthreads();
    if (tid < 64) {
        float sden = den_s[tid] + den_s[64 + tid] + den_s[128 + tid] + den_s[192 + tid];
        DEN[(size_t)(n0 + tid) * HEADS + h] = sden;
    }
}

// ---------------------------------------------------------------------------
// Kernel 3: out[n][d] = (1/8) * sum_h NUM[n][h*64+d] / DEN[n][h]
// ---------------------------------------------------------------------------
__global__ __launch_bounds__(256) void reduce_kernel(
    const float* __restrict__ NUM, const float* __restrict__ DEN,
    float* __restrict__ out)
{
    const int g = blockIdx.x * 256 + threadIdx.x;
    const int n = g >> 6;
    const int d = g & 63;
    float acc = 0.0f;
#pragma unroll
    for (int hh = 0; hh < HEADS; ++hh)
        acc += NUM[(size_t)n * PROJ + hh * 64 + d] / DEN[(size_t)n * HEADS + hh];
    out[g] = acc * 0.125f;
}

extern "C" void kernel_launch(void* const* d_in, const int* in_sizes, int n_in,
                              void* d_out, int out_size, void* d_ws, size_t ws_size,
                              hipStream_t stream) {
    (void)in_sizes; (void)n_in; (void)out_size; (void)ws_size;
    const float* X  = (const float*)d_in[0];
    const float* Wq = (const float*)d_in[1];
    const float* bq = (const float*)d_in[2];
    const float* Wk = (const float*)d_in[3];
    const float* bk = (const float*)d_in[4];
    const float* Wv = (const float*)d_in[5];
    const float* bv = (const float*)d_in[6];
    float* out = (float*)d_out;

    // workspace layout (floats): Q, K, V, NUM each N*PROJ; DEN N*HEADS
    float* Q   = (float*)d_ws;
    float* K   = Q + (size_t)N_TOK * PROJ;
    float* V   = K + (size_t)N_TOK * PROJ;
    float* NUM = V + (size_t)N_TOK * PROJ;
    float* DEN = NUM + (size_t)N_TOK * PROJ;
    // total: 4*2097152 + 32768 floats = ~33.7 MB

    proj_kernel<<<dim3(PROJ / 64, N_TOK / 64, 3), 256, 0, stream>>>(
        X, Wq, bq, Wk, bk, Wv, bv, Q, K, V);
    attn_kernel<<<dim3(N_TOK / 64, HEADS), 256, 0, stream>>>(Q, K, V, NUM, DEN);
    reduce_kernel<<<dim3(N_TOK * OUT_CH / 256), 256, 0, stream>>>(NUM, DEN, out);
}

// Round 2
// 218.815 us; speedup vs baseline: 3.1233x; 3.1233x over previous
//
#include <hip/hip_runtime.h>
#include <hip/hip_bf16.h>
#include <math.h>

#define N_TOK 4096
#define IN_CH 256
#define OUT_CH 64
#define HEADS 8
#define PROJ (OUT_CH * HEADS) /* 512 */

typedef float f32x4 __attribute__((ext_vector_type(4)));
typedef __bf16 bf16x8 __attribute__((ext_vector_type(8)));
typedef unsigned short ushort_t;

__device__ inline ushort_t bf16rne(float x) {
    unsigned u = __float_as_uint(x);
    unsigned r = (u + 0x7FFFu + ((u >> 16) & 1u)) >> 16;
    return (ushort_t)r;
}
__device__ inline float bfu_to_f(ushort_t b) {
    return __uint_as_float(((unsigned)b) << 16);
}

// ---------------------------------------------------------------------------
// Kernel 1: Q/K/V projections (fp32 FMA), emitting bf16.
//   z=0 -> Qb [N][PROJ] bf16 row-major
//   z=1 -> Kb [N][PROJ] bf16 row-major
//   z=2 -> Vt [HEADS][64][N] bf16 (transposed per head)
// grid (PROJ/64, N/64, 3), block 256.  64x64 tile, 4x4 per thread.
// ---------------------------------------------------------------------------
__global__ __launch_bounds__(256) void proj_kernel(
    const float* __restrict__ X,
    const float* __restrict__ Wq, const float* __restrict__ bq,
    const float* __restrict__ Wk, const float* __restrict__ bk,
    const float* __restrict__ Wv, const float* __restrict__ bv,
    ushort_t* __restrict__ Qb, ushort_t* __restrict__ Kb,
    ushort_t* __restrict__ Vt)
{
    const int z = blockIdx.z;
    const float* W    = (z == 0) ? Wq : (z == 1) ? Wk : Wv;
    const float* bias = (z == 0) ? bq : (z == 1) ? bk : bv;

    const int c0 = blockIdx.x * 64;  // proj-dim tile
    const int n0 = blockIdx.y * 64;  // token tile

    __shared__ float Xs[64 * 68];  // [k][m]
    __shared__ float Ws[64 * 68];  // [k][n]

    const int tid = threadIdx.x;
    const int tx = tid & 15, ty = tid >> 4;
    const int lc = tid & 15, lr = tid >> 4;

    float acc[4][4] = {};

    for (int kt = 0; kt < IN_CH / 64; ++kt) {
        const int k0 = kt * 64;
        __syncthreads();
#pragma unroll
        for (int r = 0; r < 4; ++r) {
            const int row = lr + r * 16;
            float4 f = *(const float4*)&X[(size_t)(n0 + row) * IN_CH + k0 + 4 * lc];
            Xs[(4 * lc + 0) * 68 + row] = f.x;
            Xs[(4 * lc + 1) * 68 + row] = f.y;
            Xs[(4 * lc + 2) * 68 + row] = f.z;
            Xs[(4 * lc + 3) * 68 + row] = f.w;
            float4 g = *(const float4*)&W[(size_t)(c0 + row) * IN_CH + k0 + 4 * lc];
            Ws[(4 * lc + 0) * 68 + row] = g.x;
            Ws[(4 * lc + 1) * 68 + row] = g.y;
            Ws[(4 * lc + 2) * 68 + row] = g.z;
            Ws[(4 * lc + 3) * 68 + row] = g.w;
        }
        __syncthreads();
#pragma unroll 8
        for (int k = 0; k < 64; ++k) {
            float4 a = *(const float4*)&Xs[k * 68 + 4 * ty];
            float4 b = *(const float4*)&Ws[k * 68 + 4 * tx];
            float av[4] = {a.x, a.y, a.z, a.w};
            float bv4[4] = {b.x, b.y, b.z, b.w};
#pragma unroll
            for (int i = 0; i < 4; ++i)
#pragma unroll
                for (int j = 0; j < 4; ++j)
                    acc[i][j] = fmaf(av[i], bv4[j], acc[i][j]);
        }
    }

    float4 bb = *(const float4*)&bias[c0 + 4 * tx];
    float bbv[4] = {bb.x, bb.y, bb.z, bb.w};
#pragma unroll
    for (int i = 0; i < 4; ++i)
#pragma unroll
        for (int j = 0; j < 4; ++j)
            acc[i][j] += bbv[j];

    if (z < 2) {
        ushort_t* out = (z == 0) ? Qb : Kb;
#pragma unroll
        for (int i = 0; i < 4; ++i) {
            ushort4 pk;
            pk.x = bf16rne(acc[i][0]);
            pk.y = bf16rne(acc[i][1]);
            pk.z = bf16rne(acc[i][2]);
            pk.w = bf16rne(acc[i][3]);
            *(ushort4*)&out[(size_t)(n0 + 4 * ty + i) * PROJ + c0 + 4 * tx] = pk;
        }
    } else {
        // V transposed: Vt[h][d][n], pack along n (i index)
#pragma unroll
        for (int j = 0; j < 4; ++j) {
            const int col = c0 + 4 * tx + j;
            const int hh = col >> 6, d = col & 63;
            ushort4 pk;
            pk.x = bf16rne(acc[0][j]);
            pk.y = bf16rne(acc[1][j]);
            pk.z = bf16rne(acc[2][j]);
            pk.w = bf16rne(acc[3][j]);
            *(ushort4*)&Vt[(size_t)hh * 64 * N_TOK + (size_t)d * N_TOK + n0 + 4 * ty] = pk;
        }
    }
}

// ---------------------------------------------------------------------------
// Kernel 2: fused sigmoid attention with bf16 MFMA (16x16x32).
// grid (N/64, HEADS, 2 key-splits), block 256 (4 waves; wave w owns queries
// n0+w*16 .. +15).  Per 64-key tile:
//   phase 1: S^T frags  (A = K-tile from LDS, B = Q in registers)
//            C-layout: row = l = quad*4+reg, col = q = lane&15
//   sigmoid -> bf16, den += p, pack 4 consecutive-l -> b64 write Ps[q][l]
//   phase 2: O += P*V   (A = P from Ps (b128), B = V^T tile from LDS (b128))
// NUM unnormalized [z][N][PROJ] f32, DEN [z][N][HEADS] f32.
// LDS strides padded to 72 bf16 (144B = 9*16B: keeps 16B alignment, breaks
// power-of-2 bank aliasing).
// ---------------------------------------------------------------------------
__global__ __launch_bounds__(256, 4) void attn_kernel(
    const ushort_t* __restrict__ Qb, const ushort_t* __restrict__ Kb,
    const ushort_t* __restrict__ Vt,
    float* __restrict__ NUM, float* __restrict__ DEN)
{
    const int h = blockIdx.y;
    const int z = blockIdx.z;
    const int n0 = blockIdx.x * 64;
    const int tid = threadIdx.x;
    const int w = tid >> 6;
    const int lane = tid & 63;
    const int l15 = lane & 15;
    const int quad = lane >> 4;

    __shared__ ushort_t Ks[64 * 72];       // [l][d] bf16
    __shared__ ushort_t Vs[64 * 72];       // [d][l] bf16 (V^T tile)
    __shared__ ushort_t Ps[4][16 * 72];    // per-wave [q][l] bf16

    // Q B-fragments, register-resident for the whole kernel.
    bf16x8 qb[2];
    {
        const ushort_t* base = Qb + (size_t)(n0 + w * 16 + l15) * PROJ + h * 64 + quad * 8;
        qb[0] = *(const bf16x8*)(base);
        qb[1] = *(const bf16x8*)(base + 32);
    }

    f32x4 o[4] = {{0.f, 0.f, 0.f, 0.f}, {0.f, 0.f, 0.f, 0.f},
                  {0.f, 0.f, 0.f, 0.f}, {0.f, 0.f, 0.f, 0.f}};
    float den = 0.f;

    const int srow = tid >> 2;          // 0..63
    const int scol = (tid & 3) * 16;    // 0,16,32,48

    for (int lt = 0; lt < 32; ++lt) {
        const int l0 = z * 2048 + lt * 64;
        __syncthreads();
        {
            const uint4* kg = (const uint4*)(Kb + (size_t)(l0 + srow) * PROJ + h * 64 + scol);
            uint4 k0 = kg[0], k1 = kg[1];
            const uint4* vg = (const uint4*)(Vt + (size_t)h * 64 * N_TOK + (size_t)srow * N_TOK + l0 + scol);
            uint4 v0 = vg[0], v1 = vg[1];
            uint4* kd = (uint4*)&Ks[srow * 72 + scol];
            kd[0] = k0; kd[1] = k1;
            uint4* vd = (uint4*)&Vs[srow * 72 + scol];
            vd[0] = v0; vd[1] = v1;
        }
        __syncthreads();

        // phase 1: S^T = K . Q^T  (D[l][q])
        f32x4 s[4] = {{0.f, 0.f, 0.f, 0.f}, {0.f, 0.f, 0.f, 0.f},
                      {0.f, 0.f, 0.f, 0.f}, {0.f, 0.f, 0.f, 0.f}};
#pragma unroll
        for (int c = 0; c < 2; ++c) {
#pragma unroll
            for (int f = 0; f < 4; ++f) {
                bf16x8 ka = *(const bf16x8*)&Ks[(f * 16 + l15) * 72 + c * 32 + quad * 8];
                s[f] = __builtin_amdgcn_mfma_f32_16x16x32_bf16(ka, qb[c], s[f], 0, 0, 0);
            }
        }

        // sigmoid, bf16 round, den accumulate, pack 4 consecutive l -> b64
        ushort_t* pw = &Ps[w][l15 * 72];
#pragma unroll
        for (int f = 0; f < 4; ++f) {
            ushort4 pk;
            {
                float p0 = 1.0f / (1.0f + __expf(-s[f][0]));
                float p1 = 1.0f / (1.0f + __expf(-s[f][1]));
                float p2 = 1.0f / (1.0f + __expf(-s[f][2]));
                float p3 = 1.0f / (1.0f + __expf(-s[f][3]));
                pk.x = bf16rne(p0); pk.y = bf16rne(p1);
                pk.z = bf16rne(p2); pk.w = bf16rne(p3);
                den += bfu_to_f(pk.x) + bfu_to_f(pk.y) + bfu_to_f(pk.z) + bfu_to_f(pk.w);
            }
            *(ushort4*)&pw[f * 16 + quad * 4] = pk;
        }

        // phase 2: O += P . V   (A = Ps, B = Vs rows)
#pragma unroll
        for (int c = 0; c < 2; ++c) {
            bf16x8 pa = *(const bf16x8*)&Ps[w][l15 * 72 + c * 32 + quad * 8];
#pragma unroll
            for (int f = 0; f < 4; ++f) {
                bf16x8 vb = *(const bf16x8*)&Vs[(f * 16 + l15) * 72 + c * 32 + quad * 8];
                o[f] = __builtin_amdgcn_mfma_f32_16x16x32_bf16(pa, vb, o[f], 0, 0, 0);
            }
        }
    }

    // epilogue: unnormalized numerator, C-layout scatter (coalesced over lanes)
#pragma unroll
    for (int f = 0; f < 4; ++f) {
#pragma unroll
        for (int r = 0; r < 4; ++r) {
            const int q = n0 + w * 16 + quad * 4 + r;
            NUM[((size_t)z * N_TOK + q) * PROJ + h * 64 + f * 16 + l15] = o[f][r];
        }
    }
    // den: reduce across quads (different l), queries are per-lane (lane&15)
    den += __shfl_xor(den, 16);
    den += __shfl_xor(den, 32);
    if (quad == 0)
        DEN[((size_t)z * N_TOK + n0 + w * 16 + l15) * HEADS + h] = den;
}

// ---------------------------------------------------------------------------
// Kernel 3: out[n][d] = (1/8) * sum_h (NUM0+NUM1)/(DEN0+DEN1)
// ---------------------------------------------------------------------------
__global__ __launch_bounds__(256) void reduce_kernel(
    const float* __restrict__ NUM, const float* __restrict__ DEN,
    float* __restrict__ out)
{
    const int g = blockIdx.x * 256 + threadIdx.x;
    const int n = g >> 6;
    const int d = g & 63;
    float acc = 0.0f;
#pragma unroll
    for (int hh = 0; hh < HEADS; ++hh) {
        float num = NUM[(size_t)n * PROJ + hh * 64 + d] +
                    NUM[((size_t)N_TOK + n) * PROJ + hh * 64 + d];
        float dd = DEN[(size_t)n * HEADS + hh] +
                   DEN[((size_t)N_TOK + n) * HEADS + hh];
        acc += num / dd;
    }
    out[g] = acc * 0.125f;
}

extern "C" void kernel_launch(void* const* d_in, const int* in_sizes, int n_in,
                              void* d_out, int out_size, void* d_ws, size_t ws_size,
                              hipStream_t stream) {
    (void)in_sizes; (void)n_in; (void)out_size; (void)ws_size;
    const float* X  = (const float*)d_in[0];
    const float* Wq = (const float*)d_in[1];
    const float* bq = (const float*)d_in[2];
    const float* Wk = (const float*)d_in[3];
    const float* bk = (const float*)d_in[4];
    const float* Wv = (const float*)d_in[5];
    const float* bv = (const float*)d_in[6];
    float* out = (float*)d_out;

    // workspace layout: NUM [2][N][PROJ] f32, DEN [2][N][HEADS] f32,
    //                   Qb/Kb [N][PROJ] bf16, Vt [H][64][N] bf16
    float* NUM = (float*)d_ws;                       // 16 MB
    float* DEN = NUM + (size_t)2 * N_TOK * PROJ;     // 256 KB
    ushort_t* Qb = (ushort_t*)(DEN + (size_t)2 * N_TOK * HEADS);
    ushort_t* Kb = Qb + (size_t)N_TOK * PROJ;        // 4 MB each
    ushort_t* Vt = Kb + (size_t)N_TOK * PROJ;

    proj_kernel<<<dim3(PROJ / 64, N_TOK / 64, 3), 256, 0, stream>>>(
        X, Wq, bq, Wk, bk, Wv, bv, Qb, Kb, Vt);
    attn_kernel<<<dim3(N_TOK / 64, HEADS, 2), 256, 0, stream>>>(
        Qb, Kb, Vt, NUM, DEN);
    reduce_kernel<<<dim3(N_TOK * OUT_CH / 256), 256, 0, stream>>>(NUM, DEN, out);
}

// Round 3
// 166.217 us; speedup vs baseline: 4.1116x; 1.3164x over previous
//
#include <hip/hip_runtime.h>
#include <hip/hip_bf16.h>
#include <math.h>

#define N_TOK 4096
#define IN_CH 256
#define OUT_CH 64
#define HEADS 8
#define PROJ (OUT_CH * HEADS) /* 512 */

typedef float f32x4 __attribute__((ext_vector_type(4)));
typedef __bf16 bf16x8 __attribute__((ext_vector_type(8)));
typedef unsigned short ushort_t;

__device__ inline ushort_t bf16rne(float x) {
    unsigned u = __float_as_uint(x);
    unsigned r = (u + 0x7FFFu + ((u >> 16) & 1u)) >> 16;
    return (ushort_t)r;
}

// ---------------------------------------------------------------------------
// Kernel 0: cast X and Wq/Wk/Wv to bf16 (RNE).  Vec4 grid-flat.
//   Xb [N][IN_CH], Wb [3][PROJ][IN_CH]
// ---------------------------------------------------------------------------
__global__ __launch_bounds__(256) void cast_kernel(
    const float* __restrict__ X,
    const float* __restrict__ Wq, const float* __restrict__ Wk,
    const float* __restrict__ Wv,
    ushort_t* __restrict__ Xb, ushort_t* __restrict__ Wb)
{
    int i = blockIdx.x * 256 + threadIdx.x;  // vec4 index
    const float4* src;
    ushort_t* dst;
    if (i < 262144) { src = (const float4*)X; dst = Xb; }
    else if (i < 294912) { src = (const float4*)Wq; dst = Wb;          i -= 262144; }
    else if (i < 327680) { src = (const float4*)Wk; dst = Wb + 131072; i -= 294912; }
    else                 { src = (const float4*)Wv; dst = Wb + 262144; i -= 327680; }
    float4 v = src[i];
    ushort4 pk;
    pk.x = bf16rne(v.x); pk.y = bf16rne(v.y);
    pk.z = bf16rne(v.z); pk.w = bf16rne(v.w);
    *(ushort4*)&dst[(size_t)i * 4] = pk;
}

// ---------------------------------------------------------------------------
// Kernel 1: Q/K/V projections via bf16 MFMA, no LDS, no barriers.
// grid (PROJ/64, N/64, 3), block 256 (4 waves).  Wave w: 16 tokens x 64 cols.
// A = X rows (A[m=token][k]), B = W rows (B[k][n=c] from row-major W[c][k]).
// K=256 -> 8 MFMA k-steps, frags loaded straight from L2-resident bf16.
//   z=0 -> Qb [N][PROJ], z=1 -> Kb [N][PROJ], z=2 -> Vt [HEADS][64][N]
// ---------------------------------------------------------------------------
__global__ __launch_bounds__(256) void proj_mfma_kernel(
    const ushort_t* __restrict__ Xb, const ushort_t* __restrict__ Wb,
    const float* __restrict__ bq, const float* __restrict__ bk,
    const float* __restrict__ bv,
    ushort_t* __restrict__ Qb, ushort_t* __restrict__ Kb,
    ushort_t* __restrict__ Vt)
{
    const int z = blockIdx.z;
    const float* bias = (z == 0) ? bq : (z == 1) ? bk : bv;
    const int c0 = blockIdx.x * 64;
    const int n0 = blockIdx.y * 64;

    const int tid = threadIdx.x;
    const int w = tid >> 6;
    const int lane = tid & 63;
    const int l15 = lane & 15;
    const int quad = lane >> 4;

    const ushort_t* xrow = Xb + (size_t)(n0 + w * 16 + l15) * IN_CH + quad * 8;
    const ushort_t* wb = Wb + (size_t)z * PROJ * IN_CH;
    const ushort_t* crow[4];
#pragma unroll
    for (int f = 0; f < 4; ++f)
        crow[f] = wb + (size_t)(c0 + f * 16 + l15) * IN_CH + quad * 8;

    f32x4 acc[4] = {{0.f, 0.f, 0.f, 0.f}, {0.f, 0.f, 0.f, 0.f},
                    {0.f, 0.f, 0.f, 0.f}, {0.f, 0.f, 0.f, 0.f}};

#pragma unroll
    for (int k8 = 0; k8 < 8; ++k8) {
        bf16x8 a = *(const bf16x8*)(xrow + k8 * 32);
#pragma unroll
        for (int f = 0; f < 4; ++f) {
            bf16x8 b = *(const bf16x8*)(crow[f] + k8 * 32);
            acc[f] = __builtin_amdgcn_mfma_f32_16x16x32_bf16(a, b, acc[f], 0, 0, 0);
        }
    }

    if (z < 2) {
        ushort_t* out = z ? Kb : Qb;
#pragma unroll
        for (int f = 0; f < 4; ++f) {
            const float bb = bias[c0 + f * 16 + l15];
#pragma unroll
            for (int r = 0; r < 4; ++r) {
                const int tok = n0 + w * 16 + quad * 4 + r;
                out[(size_t)tok * PROJ + c0 + f * 16 + l15] = bf16rne(acc[f][r] + bb);
            }
        }
    } else {
#pragma unroll
        for (int f = 0; f < 4; ++f) {
            const int c = c0 + f * 16 + l15;   // h*64 + d
            const float bb = bias[c];
            ushort4 pk;
            pk.x = bf16rne(acc[f][0] + bb);
            pk.y = bf16rne(acc[f][1] + bb);
            pk.z = bf16rne(acc[f][2] + bb);
            pk.w = bf16rne(acc[f][3] + bb);
            *(ushort4*)&Vt[(size_t)c * N_TOK + n0 + w * 16 + quad * 4] = pk;
        }
    }
}

// ---------------------------------------------------------------------------
// Kernel 2: fused sigmoid attention with bf16 MFMA (16x16x32).
// grid (N/64, HEADS, 2 key-splits), block 256 (4 waves; wave w owns queries
// n0+w*16 .. +15).
// LDS K/V tiles: 64 rows x 128B, XOR-swizzled (phys chunk = chunk ^ (row&7))
// -> conflict-free b128 staging stores and frag reads.  Swizzle masks are
// per-lane constants (frag row = f*16+l15, 16 = 0 mod 8).
// Sigmoid: rcpf(1+expf(-s)) + ties-away bf16 round + v_perm pack; den
// accumulated in fp32 before rounding.
// ---------------------------------------------------------------------------
__global__ __launch_bounds__(256, 4) void attn_kernel(
    const ushort_t* __restrict__ Qb, const ushort_t* __restrict__ Kb,
    const ushort_t* __restrict__ Vt,
    float* __restrict__ NUM, float* __restrict__ DEN)
{
    const int h = blockIdx.y;
    const int z = blockIdx.z;
    const int n0 = blockIdx.x * 64;
    const int tid = threadIdx.x;
    const int w = tid >> 6;
    const int lane = tid & 63;
    const int l15 = lane & 15;
    const int quad = lane >> 4;

    __shared__ ushort_t Ks[64 * 64];      // [l][d] bf16, xor-swizzled chunks
    __shared__ ushort_t Vs[64 * 64];      // [d][l] bf16, xor-swizzled chunks
    __shared__ ushort_t Ps[4][16 * 72];   // per-wave [q][l] bf16 (144B rows)

    // Q B-fragments, register-resident.
    bf16x8 qb[2];
    {
        const ushort_t* base = Qb + (size_t)(n0 + w * 16 + l15) * PROJ + h * 64 + quad * 8;
        qb[0] = *(const bf16x8*)(base);
        qb[1] = *(const bf16x8*)(base + 32);
    }

    f32x4 o[4] = {{0.f, 0.f, 0.f, 0.f}, {0.f, 0.f, 0.f, 0.f},
                  {0.f, 0.f, 0.f, 0.f}, {0.f, 0.f, 0.f, 0.f}};
    float den = 0.f;

    // staging geometry: thread -> (row, 2 consecutive chunks), xor-swizzled
    const int srow = tid >> 2;
    const int sc2 = (tid & 3) * 2;
    const int sp0 = (sc2 ^ (srow & 7)) * 8;        // ushort offset of chunk
    const int sp1 = ((sc2 + 1) ^ (srow & 7)) * 8;
    // read swizzle: frag row = f*16 + l15 -> mask = l15&7 (per-lane const)
    const int xm = l15 & 7;
    const int rofA = (quad ^ xm) * 8;              // c = 0 chunk
    const int rofB = ((4 + quad) ^ xm) * 8;        // c = 1 chunk

    const ushort_t* kgbase = Kb + (size_t)h * 64 + sc2 * 8;
    const ushort_t* vgbase = Vt + (size_t)h * 64 * N_TOK + (size_t)srow * N_TOK + sc2 * 8;

    for (int lt = 0; lt < 32; ++lt) {
        const int l0 = z * 2048 + lt * 64;
        __syncthreads();
        {
            const uint4* kg = (const uint4*)(kgbase + (size_t)(l0 + srow) * PROJ);
            uint4 k0 = kg[0], k1 = kg[1];
            const uint4* vg = (const uint4*)(vgbase + l0);
            uint4 v0 = vg[0], v1 = vg[1];
            *(uint4*)&Ks[srow * 64 + sp0] = k0;
            *(uint4*)&Ks[srow * 64 + sp1] = k1;
            *(uint4*)&Vs[srow * 64 + sp0] = v0;
            *(uint4*)&Vs[srow * 64 + sp1] = v1;
        }
        __syncthreads();

        // phase 1: S^T = K . Q^T  (D[l][q])
        f32x4 s[4] = {{0.f, 0.f, 0.f, 0.f}, {0.f, 0.f, 0.f, 0.f},
                      {0.f, 0.f, 0.f, 0.f}, {0.f, 0.f, 0.f, 0.f}};
#pragma unroll
        for (int f = 0; f < 4; ++f) {
            bf16x8 ka = *(const bf16x8*)&Ks[(f * 16 + l15) * 64 + rofA];
            s[f] = __builtin_amdgcn_mfma_f32_16x16x32_bf16(ka, qb[0], s[f], 0, 0, 0);
        }
#pragma unroll
        for (int f = 0; f < 4; ++f) {
            bf16x8 ka = *(const bf16x8*)&Ks[(f * 16 + l15) * 64 + rofB];
            s[f] = __builtin_amdgcn_mfma_f32_16x16x32_bf16(ka, qb[1], s[f], 0, 0, 0);
        }

        // sigmoid -> bf16 (ties-away round), den accumulate (fp32), pack
        ushort_t* pw = &Ps[w][l15 * 72];
#pragma unroll
        for (int f = 0; f < 4; ++f) {
            float p0 = __builtin_amdgcn_rcpf(1.0f + __expf(-s[f][0]));
            float p1 = __builtin_amdgcn_rcpf(1.0f + __expf(-s[f][1]));
            float p2 = __builtin_amdgcn_rcpf(1.0f + __expf(-s[f][2]));
            float p3 = __builtin_amdgcn_rcpf(1.0f + __expf(-s[f][3]));
            den += (p0 + p1) + (p2 + p3);
            unsigned u0 = __float_as_uint(p0) + 0x8000u;
            unsigned u1 = __float_as_uint(p1) + 0x8000u;
            unsigned u2 = __float_as_uint(p2) + 0x8000u;
            unsigned u3 = __float_as_uint(p3) + 0x8000u;
            uint2 pk;
            pk.x = __builtin_amdgcn_perm(u1, u0, 0x07060302u);
            pk.y = __builtin_amdgcn_perm(u3, u2, 0x07060302u);
            *(uint2*)&pw[f * 16 + quad * 4] = pk;
        }

        // phase 2: O += P . V   (A = Ps rows, B = Vs rows)
#pragma unroll
        for (int c = 0; c < 2; ++c) {
            bf16x8 pa = *(const bf16x8*)&Ps[w][l15 * 72 + c * 32 + quad * 8];
            const int rof = c ? rofB : rofA;
#pragma unroll
            for (int f = 0; f < 4; ++f) {
                bf16x8 vb = *(const bf16x8*)&Vs[(f * 16 + l15) * 64 + rof];
                o[f] = __builtin_amdgcn_mfma_f32_16x16x32_bf16(pa, vb, o[f], 0, 0, 0);
            }
        }
    }

    // epilogue: unnormalized numerator
#pragma unroll
    for (int f = 0; f < 4; ++f) {
#pragma unroll
        for (int r = 0; r < 4; ++r) {
            const int q = n0 + w * 16 + quad * 4 + r;
            NUM[((size_t)z * N_TOK + q) * PROJ + h * 64 + f * 16 + l15] = o[f][r];
        }
    }
    den += __shfl_xor(den, 16);
    den += __shfl_xor(den, 32);
    if (quad == 0)
        DEN[((size_t)z * N_TOK + n0 + w * 16 + l15) * HEADS + h] = den;
}

// ---------------------------------------------------------------------------
// Kernel 3: out[n][d] = (1/8) * sum_h (NUM0+NUM1)/(DEN0+DEN1)
// ---------------------------------------------------------------------------
__global__ __launch_bounds__(256) void reduce_kernel(
    const float* __restrict__ NUM, const float* __restrict__ DEN,
    float* __restrict__ out)
{
    const int g = blockIdx.x * 256 + threadIdx.x;
    const int n = g >> 6;
    const int d = g & 63;
    float acc = 0.0f;
#pragma unroll
    for (int hh = 0; hh < HEADS; ++hh) {
        float num = NUM[(size_t)n * PROJ + hh * 64 + d] +
                    NUM[((size_t)N_TOK + n) * PROJ + hh * 64 + d];
        float dd = DEN[(size_t)n * HEADS + hh] +
                   DEN[((size_t)N_TOK + n) * HEADS + hh];
        acc += num / dd;
    }
    out[g] = acc * 0.125f;
}

extern "C" void kernel_launch(void* const* d_in, const int* in_sizes, int n_in,
                              void* d_out, int out_size, void* d_ws, size_t ws_size,
                              hipStream_t stream) {
    (void)in_sizes; (void)n_in; (void)out_size; (void)ws_size;
    const float* X  = (const float*)d_in[0];
    const float* Wq = (const float*)d_in[1];
    const float* bq = (const float*)d_in[2];
    const float* Wk = (const float*)d_in[3];
    const float* bk = (const float*)d_in[4];
    const float* Wv = (const float*)d_in[5];
    const float* bv = (const float*)d_in[6];
    float* out = (float*)d_out;

    // ws layout (32.5 MB total):
    float* NUM = (float*)d_ws;                              // [2][N][PROJ] f32
    float* DEN = NUM + (size_t)2 * N_TOK * PROJ;            // [2][N][HEADS] f32
    ushort_t* Qb = (ushort_t*)(DEN + (size_t)2 * N_TOK * HEADS);
    ushort_t* Kb = Qb + (size_t)N_TOK * PROJ;
    ushort_t* Vt = Kb + (size_t)N_TOK * PROJ;               // [H][64][N]
    ushort_t* Xb = Vt + (size_t)N_TOK * PROJ;               // [N][IN_CH]
    ushort_t* Wb = Xb + (size_t)N_TOK * IN_CH;              // [3][PROJ][IN_CH]

    cast_kernel<<<dim3(1408), 256, 0, stream>>>(X, Wq, Wk, Wv, Xb, Wb);
    proj_mfma_kernel<<<dim3(PROJ / 64, N_TOK / 64, 3), 256, 0, stream>>>(
        Xb, Wb, bq, bk, bv, Qb, Kb, Vt);
    attn_kernel<<<dim3(N_TOK / 64, HEADS, 2), 256, 0, stream>>>(
        Qb, Kb, Vt, NUM, DEN);
    reduce_kernel<<<dim3(N_TOK * OUT_CH / 256), 256, 0, stream>>>(NUM, DEN, out);
}

// Round 4
// 144.105 us; speedup vs baseline: 4.7425x; 1.1534x over previous
//
#include <hip/hip_runtime.h>
#include <hip/hip_bf16.h>
#include <math.h>

#define N_TOK 4096
#define IN_CH 256
#define OUT_CH 64
#define HEADS 8
#define PROJ (OUT_CH * HEADS) /* 512 */
#define NLOG2E -1.44269504088896340736f

typedef float f32x4 __attribute__((ext_vector_type(4)));
typedef __bf16 bf16x8 __attribute__((ext_vector_type(8)));
typedef unsigned short ushort_t;

__device__ inline ushort_t bf16rne(float x) {
    unsigned u = __float_as_uint(x);
    unsigned r = (u + 0x7FFFu + ((u >> 16) & 1u)) >> 16;
    return (ushort_t)r;
}

// ---------------------------------------------------------------------------
// Kernel 0: cast X / Wq / Wk / Wv to bf16 AND pre-permute into MFMA fragment
// order:  flat index (((g*8 + k8)*4 + quad)*16 + t)*8  (g = 16-row group).
//   Xa [N/16 groups][8][4][16][8]   (A-operand order, rows = tokens)
//   Wp [3][PROJ/16 groups][8][4][16][8]  (B-operand order, rows = out-cols)
// Wq additionally scaled by -log2(e) so attention scores come out as
// t = -log2e * (q.k)  ->  sigmoid = rcp(1 + exp2(t)).
// Writes fully coalesced; reads are 16-row x 32B gathers (one-time, 5.5 MB).
// ---------------------------------------------------------------------------
__global__ __launch_bounds__(256) void cast_pack_kernel(
    const float* __restrict__ X,
    const float* __restrict__ Wq, const float* __restrict__ Wk,
    const float* __restrict__ Wv,
    ushort_t* __restrict__ Xa, ushort_t* __restrict__ Wp)
{
    const int i = blockIdx.x * 256 + threadIdx.x;
    const float* src;
    ushort_t* dst;
    float scale = 1.0f;
    if (i < 131072) {                       // X part: N*IN_CH/8 packs
        const int t = i & 15, quad = (i >> 4) & 3, k8 = (i >> 6) & 7, g = i >> 9;
        src = X + (size_t)(g * 16 + t) * IN_CH + k8 * 32 + quad * 8;
        dst = Xa + (size_t)i * 8;
    } else {                                // W part: 3*PROJ*IN_CH/8 packs
        const int j = i - 131072;
        const int z = j >> 14;
        const int r = j & 16383;
        const int cl = r & 15, quad = (r >> 4) & 3, k8 = (r >> 6) & 7, gc = r >> 9;
        const float* W = (z == 0) ? Wq : (z == 1) ? Wk : Wv;
        src = W + (size_t)(gc * 16 + cl) * IN_CH + k8 * 32 + quad * 8;
        dst = Wp + (size_t)z * 131072 * 8 + (size_t)r * 8;
        if (z == 0) scale = NLOG2E;
    }
    float4 a = *(const float4*)src;
    float4 b = *(const float4*)(src + 4);
    ushort_t pk[8];
    pk[0] = bf16rne(a.x * scale); pk[1] = bf16rne(a.y * scale);
    pk[2] = bf16rne(a.z * scale); pk[3] = bf16rne(a.w * scale);
    pk[4] = bf16rne(b.x * scale); pk[5] = bf16rne(b.y * scale);
    pk[6] = bf16rne(b.z * scale); pk[7] = bf16rne(b.w * scale);
    *(uint4*)dst = *(uint4*)pk;
}

// ---------------------------------------------------------------------------
// Kernel 1: Q/K/V projections via bf16 MFMA.  All loads are wave-contiguous
// 1KB dwordx4 from the frag-packed Xa/Wp (no LDS, no barriers, no per-lane
// address arithmetic beyond one base).
// grid (PROJ/64, N/64, 3), block 256 (4 waves).  Wave w: 16 tokens x 64 cols.
//   z=0 -> Qb [N][PROJ] (pre-scaled by -log2e), z=1 -> Kb, z=2 -> Vt [H][64][N]
// ---------------------------------------------------------------------------
__global__ __launch_bounds__(256) void proj_mfma_kernel(
    const ushort_t* __restrict__ Xa, const ushort_t* __restrict__ Wp,
    const float* __restrict__ bq, const float* __restrict__ bk,
    const float* __restrict__ bv,
    ushort_t* __restrict__ Qb, ushort_t* __restrict__ Kb,
    ushort_t* __restrict__ Vt)
{
    const int z = blockIdx.z;
    const float* bias = (z == 0) ? bq : (z == 1) ? bk : bv;
    const float bscale = (z == 0) ? NLOG2E : 1.0f;
    const int c0 = blockIdx.x * 64;
    const int n0 = blockIdx.y * 64;

    const int tid = threadIdx.x;
    const int w = tid >> 6;
    const int lane = tid & 63;
    const int l15 = lane & 15;
    const int quad = lane >> 4;

    const ushort_t* xa = Xa + (size_t)(blockIdx.y * 4 + w) * 4096 + quad * 128 + l15 * 8;
    const ushort_t* wp0 = Wp + (size_t)z * 131072 * 8 +
                          (size_t)(blockIdx.x * 4) * 4096 + quad * 128 + l15 * 8;

    f32x4 acc[4] = {{0.f, 0.f, 0.f, 0.f}, {0.f, 0.f, 0.f, 0.f},
                    {0.f, 0.f, 0.f, 0.f}, {0.f, 0.f, 0.f, 0.f}};

#pragma unroll
    for (int k8 = 0; k8 < 8; ++k8) {
        bf16x8 a = *(const bf16x8*)(xa + k8 * 512);
#pragma unroll
        for (int f = 0; f < 4; ++f) {
            bf16x8 b = *(const bf16x8*)(wp0 + f * 4096 + k8 * 512);
            acc[f] = __builtin_amdgcn_mfma_f32_16x16x32_bf16(a, b, acc[f], 0, 0, 0);
        }
    }

    if (z < 2) {
        ushort_t* out = z ? Kb : Qb;
#pragma unroll
        for (int f = 0; f < 4; ++f) {
            const float bb = bias[c0 + f * 16 + l15] * bscale;
#pragma unroll
            for (int r = 0; r < 4; ++r) {
                const int tok = n0 + w * 16 + quad * 4 + r;
                out[(size_t)tok * PROJ + c0 + f * 16 + l15] = bf16rne(acc[f][r] + bb);
            }
        }
    } else {
#pragma unroll
        for (int f = 0; f < 4; ++f) {
            const int c = c0 + f * 16 + l15;   // h*64 + d
            const float bb = bias[c];
            ushort4 pk;
            pk.x = bf16rne(acc[f][0] + bb);
            pk.y = bf16rne(acc[f][1] + bb);
            pk.z = bf16rne(acc[f][2] + bb);
            pk.w = bf16rne(acc[f][3] + bb);
            *(ushort4*)&Vt[(size_t)c * N_TOK + n0 + w * 16 + quad * 4] = pk;
        }
    }
}

// ---------------------------------------------------------------------------
// Kernel 2: fused sigmoid attention with bf16 MFMA (16x16x32).
// grid (N/64, HEADS, 2 key-splits), block 256 (4 waves; wave w owns queries
// n0+w*16 .. +15).
// Scores arrive pre-scaled: t = -log2e*(q.k) -> p = rcpf(1 + exp2f(t)).
// DEN computed by MFMA against a ones-B fragment (row-sum of bf16 P).
// LDS K/V tiles XOR-swizzled (conflict-free b128 staging + frag reads).
// ---------------------------------------------------------------------------
__global__ __launch_bounds__(256, 4) void attn_kernel(
    const ushort_t* __restrict__ Qb, const ushort_t* __restrict__ Kb,
    const ushort_t* __restrict__ Vt,
    float* __restrict__ NUM, float* __restrict__ DEN)
{
    const int h = blockIdx.y;
    const int z = blockIdx.z;
    const int n0 = blockIdx.x * 64;
    const int tid = threadIdx.x;
    const int w = tid >> 6;
    const int lane = tid & 63;
    const int l15 = lane & 15;
    const int quad = lane >> 4;

    __shared__ ushort_t Ks[64 * 64];      // [l][d] bf16, xor-swizzled chunks
    __shared__ ushort_t Vs[64 * 64];      // [d][l] bf16, xor-swizzled chunks
    __shared__ ushort_t Ps[4][16 * 72];   // per-wave [q][l] bf16 (144B rows)

    // Q B-fragments, register-resident (pre-scaled by -log2e).
    bf16x8 qb[2];
    {
        const ushort_t* base = Qb + (size_t)(n0 + w * 16 + l15) * PROJ + h * 64 + quad * 8;
        qb[0] = *(const bf16x8*)(base);
        qb[1] = *(const bf16x8*)(base + 32);
    }

    bf16x8 onesv;
#pragma unroll
    for (int j = 0; j < 8; ++j) onesv[j] = (__bf16)1.0f;

    f32x4 o[4] = {{0.f, 0.f, 0.f, 0.f}, {0.f, 0.f, 0.f, 0.f},
                  {0.f, 0.f, 0.f, 0.f}, {0.f, 0.f, 0.f, 0.f}};
    f32x4 dacc = {0.f, 0.f, 0.f, 0.f};

    // staging geometry: thread -> (row, 2 consecutive chunks), xor-swizzled
    const int srow = tid >> 2;
    const int sc2 = (tid & 3) * 2;
    const int sp0 = (sc2 ^ (srow & 7)) * 8;
    const int sp1 = ((sc2 + 1) ^ (srow & 7)) * 8;
    // read swizzle: frag row = f*16 + l15 -> mask = l15&7 (per-lane const)
    const int xm = l15 & 7;
    const int rofA = (quad ^ xm) * 8;
    const int rofB = ((4 + quad) ^ xm) * 8;

    const ushort_t* kgbase = Kb + (size_t)h * 64 + sc2 * 8;
    const ushort_t* vgbase = Vt + (size_t)h * 64 * N_TOK + (size_t)srow * N_TOK + sc2 * 8;

    for (int lt = 0; lt < 32; ++lt) {
        const int l0 = z * 2048 + lt * 64;
        __syncthreads();
        {
            const uint4* kg = (const uint4*)(kgbase + (size_t)(l0 + srow) * PROJ);
            uint4 k0 = kg[0], k1 = kg[1];
            const uint4* vg = (const uint4*)(vgbase + l0);
            uint4 v0 = vg[0], v1 = vg[1];
            *(uint4*)&Ks[srow * 64 + sp0] = k0;
            *(uint4*)&Ks[srow * 64 + sp1] = k1;
            *(uint4*)&Vs[srow * 64 + sp0] = v0;
            *(uint4*)&Vs[srow * 64 + sp1] = v1;
        }
        __syncthreads();

        // phase 1: T = -log2e * K.Q^T  (D[l][q])
        f32x4 s[4] = {{0.f, 0.f, 0.f, 0.f}, {0.f, 0.f, 0.f, 0.f},
                      {0.f, 0.f, 0.f, 0.f}, {0.f, 0.f, 0.f, 0.f}};
#pragma unroll
        for (int f = 0; f < 4; ++f) {
            bf16x8 ka = *(const bf16x8*)&Ks[(f * 16 + l15) * 64 + rofA];
            s[f] = __builtin_amdgcn_mfma_f32_16x16x32_bf16(ka, qb[0], s[f], 0, 0, 0);
        }
#pragma unroll
        for (int f = 0; f < 4; ++f) {
            bf16x8 ka = *(const bf16x8*)&Ks[(f * 16 + l15) * 64 + rofB];
            s[f] = __builtin_amdgcn_mfma_f32_16x16x32_bf16(ka, qb[1], s[f], 0, 0, 0);
        }

        // sigmoid = rcp(1 + 2^t); bf16 ties-away round; v_perm pack
        ushort_t* pw = &Ps[w][l15 * 72];
#pragma unroll
        for (int f = 0; f < 4; ++f) {
            float p0 = __builtin_amdgcn_rcpf(1.0f + __builtin_amdgcn_exp2f(s[f][0]));
            float p1 = __builtin_amdgcn_rcpf(1.0f + __builtin_amdgcn_exp2f(s[f][1]));
            float p2 = __builtin_amdgcn_rcpf(1.0f + __builtin_amdgcn_exp2f(s[f][2]));
            float p3 = __builtin_amdgcn_rcpf(1.0f + __builtin_amdgcn_exp2f(s[f][3]));
            unsigned u0 = __float_as_uint(p0) + 0x8000u;
            unsigned u1 = __float_as_uint(p1) + 0x8000u;
            unsigned u2 = __float_as_uint(p2) + 0x8000u;
            unsigned u3 = __float_as_uint(p3) + 0x8000u;
            uint2 pk;
            pk.x = __builtin_amdgcn_perm(u1, u0, 0x07060302u);
            pk.y = __builtin_amdgcn_perm(u3, u2, 0x07060302u);
            *(uint2*)&pw[f * 16 + quad * 4] = pk;
        }

        // phase 2: O += P.V ; DEN += P.1  (A = Ps rows, B = Vs rows / ones)
#pragma unroll
        for (int c = 0; c < 2; ++c) {
            bf16x8 pa = *(const bf16x8*)&Ps[w][l15 * 72 + c * 32 + quad * 8];
            const int rof = c ? rofB : rofA;
#pragma unroll
            for (int f = 0; f < 4; ++f) {
                bf16x8 vb = *(const bf16x8*)&Vs[(f * 16 + l15) * 64 + rof];
                o[f] = __builtin_amdgcn_mfma_f32_16x16x32_bf16(pa, vb, o[f], 0, 0, 0);
            }
            dacc = __builtin_amdgcn_mfma_f32_16x16x32_bf16(pa, onesv, dacc, 0, 0, 0);
        }
    }

    // epilogue: unnormalized numerator
#pragma unroll
    for (int f = 0; f < 4; ++f) {
#pragma unroll
        for (int r = 0; r < 4; ++r) {
            const int q = n0 + w * 16 + quad * 4 + r;
            NUM[((size_t)z * N_TOK + q) * PROJ + h * 64 + f * 16 + l15] = o[f][r];
        }
    }
    // DEN: dacc rows are q = quad*4+r, identical across cols; col 0 writes.
    if (l15 == 0) {
#pragma unroll
        for (int r = 0; r < 4; ++r)
            DEN[((size_t)z * N_TOK + n0 + w * 16 + quad * 4 + r) * HEADS + h] = dacc[r];
    }
}

// ---------------------------------------------------------------------------
// Kernel 3: out[n][d] = (1/8) * sum_h (NUM0+NUM1)/(DEN0+DEN1)
// ---------------------------------------------------------------------------
__global__ __launch_bounds__(256) void reduce_kernel(
    const float* __restrict__ NUM, const float* __restrict__ DEN,
    float* __restrict__ out)
{
    const int g = blockIdx.x * 256 + threadIdx.x;
    const int n = g >> 6;
    const int d = g & 63;
    float acc = 0.0f;
#pragma unroll
    for (int hh = 0; hh < HEADS; ++hh) {
        float num = NUM[(size_t)n * PROJ + hh * 64 + d] +
                    NUM[((size_t)N_TOK + n) * PROJ + hh * 64 + d];
        float dd = DEN[(size_t)n * HEADS + hh] +
                   DEN[((size_t)N_TOK + n) * HEADS + hh];
        acc += num / dd;
    }
    out[g] = acc * 0.125f;
}

extern "C" void kernel_launch(void* const* d_in, const int* in_sizes, int n_in,
                              void* d_out, int out_size, void* d_ws, size_t ws_size,
                              hipStream_t stream) {
    (void)in_sizes; (void)n_in; (void)out_size; (void)ws_size;
    const float* X  = (const float*)d_in[0];
    const float* Wq = (const float*)d_in[1];
    const float* bq = (const float*)d_in[2];
    const float* Wk = (const float*)d_in[3];
    const float* bk = (const float*)d_in[4];
    const float* Wv = (const float*)d_in[5];
    const float* bv = (const float*)d_in[6];
    float* out = (float*)d_out;

    // ws layout (~35.3 MB total):
    float* NUM = (float*)d_ws;                              // [2][N][PROJ] f32
    float* DEN = NUM + (size_t)2 * N_TOK * PROJ;            // [2][N][HEADS] f32
    ushort_t* Qb = (ushort_t*)(DEN + (size_t)2 * N_TOK * HEADS);
    ushort_t* Kb = Qb + (size_t)N_TOK * PROJ;
    ushort_t* Vt = Kb + (size_t)N_TOK * PROJ;               // [H][64][N]
    ushort_t* Xa = Vt + (size_t)N_TOK * PROJ;               // frag-packed X
    ushort_t* Wp = Xa + (size_t)N_TOK * IN_CH;              // frag-packed W x3

    cast_pack_kernel<<<dim3(704), 256, 0, stream>>>(X, Wq, Wk, Wv, Xa, Wp);
    proj_mfma_kernel<<<dim3(PROJ / 64, N_TOK / 64, 3), 256, 0, stream>>>(
        Xa, Wp, bq, bk, bv, Qb, Kb, Vt);
    attn_kernel<<<dim3(N_TOK / 64, HEADS, 2), 256, 0, stream>>>(
        Qb, Kb, Vt, NUM, DEN);
    reduce_kernel<<<dim3(N_TOK * OUT_CH / 256), 256, 0, stream>>>(NUM, DEN, out);
}

// Round 6
// 143.231 us; speedup vs baseline: 4.7715x; 1.0061x over previous
//
#include <hip/hip_runtime.h>
#include <hip/hip_bf16.h>
#include <math.h>

#define N_TOK 4096
#define IN_CH 256
#define OUT_CH 64
#define HEADS 8
#define PROJ (OUT_CH * HEADS) /* 512 */
#define NLOG2E -1.44269504088896340736f

typedef float f32x4 __attribute__((ext_vector_type(4)));
typedef __bf16 bf16x8 __attribute__((ext_vector_type(8)));
typedef unsigned short ushort_t;

__device__ inline ushort_t bf16rne(float x) {
    unsigned u = __float_as_uint(x);
    unsigned r = (u + 0x7FFFu + ((u >> 16) & 1u)) >> 16;
    return (ushort_t)r;
}

// ---------------------------------------------------------------------------
// Kernel 0: cast X / Wq / Wk / Wv to bf16 AND pre-permute into MFMA fragment
// order:  flat index (((g*8 + k8)*4 + quad)*16 + t)*8  (g = 16-row group).
// Wq additionally scaled by -log2(e) so sigmoid = rcp(1 + exp2(t)).
// ---------------------------------------------------------------------------
__global__ __launch_bounds__(256) void cast_pack_kernel(
    const float* __restrict__ X,
    const float* __restrict__ Wq, const float* __restrict__ Wk,
    const float* __restrict__ Wv,
    ushort_t* __restrict__ Xa, ushort_t* __restrict__ Wp)
{
    const int i = blockIdx.x * 256 + threadIdx.x;
    const float* src;
    ushort_t* dst;
    float scale = 1.0f;
    if (i < 131072) {                       // X part: N*IN_CH/8 packs
        const int t = i & 15, quad = (i >> 4) & 3, k8 = (i >> 6) & 7, g = i >> 9;
        src = X + (size_t)(g * 16 + t) * IN_CH + k8 * 32 + quad * 8;
        dst = Xa + (size_t)i * 8;
    } else {                                // W part: 3*PROJ*IN_CH/8 packs
        const int j = i - 131072;
        const int z = j >> 14;
        const int r = j & 16383;
        const int cl = r & 15, quad = (r >> 4) & 3, k8 = (r >> 6) & 7, gc = r >> 9;
        const float* W = (z == 0) ? Wq : (z == 1) ? Wk : Wv;
        src = W + (size_t)(gc * 16 + cl) * IN_CH + k8 * 32 + quad * 8;
        dst = Wp + (size_t)z * 131072 * 8 + (size_t)r * 8;
        if (z == 0) scale = NLOG2E;
    }
    float4 a = *(const float4*)src;
    float4 b = *(const float4*)(src + 4);
    ushort_t pk[8];
    pk[0] = bf16rne(a.x * scale); pk[1] = bf16rne(a.y * scale);
    pk[2] = bf16rne(a.z * scale); pk[3] = bf16rne(a.w * scale);
    pk[4] = bf16rne(b.x * scale); pk[5] = bf16rne(b.y * scale);
    pk[6] = bf16rne(b.z * scale); pk[7] = bf16rne(b.w * scale);
    *(uint4*)dst = *(uint4*)pk;
}

// ---------------------------------------------------------------------------
// Kernel 1: Q/K/V projections via bf16 MFMA from frag-packed Xa/Wp.
// grid (PROJ/64, N/64, 3), block 256 (4 waves).  Wave w: 16 tokens x 64 cols.
// Epilogue routes through an LDS transpose so ALL global stores are coalesced
// uint4.  NOTE: Es tile is 64x64 ushorts = 8 KB; 256 threads must store TWO
// uint4 each (R5 bug: one uint4/thread left half the tile unwritten).
//   z=0 -> Qb [N][PROJ] (pre-scaled by -log2e), z=1 -> Kb, z=2 -> Vt [H][64][N]
// ---------------------------------------------------------------------------
__global__ __launch_bounds__(256) void proj_mfma_kernel(
    const ushort_t* __restrict__ Xa, const ushort_t* __restrict__ Wp,
    const float* __restrict__ bq, const float* __restrict__ bk,
    const float* __restrict__ bv,
    ushort_t* __restrict__ Qb, ushort_t* __restrict__ Kb,
    ushort_t* __restrict__ Vt)
{
    const int z = blockIdx.z;
    const float* bias = (z == 0) ? bq : (z == 1) ? bk : bv;
    const float bscale = (z == 0) ? NLOG2E : 1.0f;
    const int c0 = blockIdx.x * 64;
    const int n0 = blockIdx.y * 64;

    const int tid = threadIdx.x;
    const int w = tid >> 6;
    const int lane = tid & 63;
    const int l15 = lane & 15;
    const int quad = lane >> 4;

    __shared__ ushort_t Es[64 * 68];   // epilogue transpose tile (8.7 KB)

    const ushort_t* xa = Xa + (size_t)(blockIdx.y * 4 + w) * 4096 + quad * 128 + l15 * 8;
    const ushort_t* wp0 = Wp + (size_t)z * 131072 * 8 +
                          (size_t)(blockIdx.x * 4) * 4096 + quad * 128 + l15 * 8;

    f32x4 acc[4] = {{0.f, 0.f, 0.f, 0.f}, {0.f, 0.f, 0.f, 0.f},
                    {0.f, 0.f, 0.f, 0.f}, {0.f, 0.f, 0.f, 0.f}};

#pragma unroll 2
    for (int k8 = 0; k8 < 8; ++k8) {
        bf16x8 a = *(const bf16x8*)(xa + k8 * 512);
#pragma unroll
        for (int f = 0; f < 4; ++f) {
            bf16x8 b = *(const bf16x8*)(wp0 + f * 4096 + k8 * 512);
            acc[f] = __builtin_amdgcn_mfma_f32_16x16x32_bf16(a, b, acc[f], 0, 0, 0);
        }
    }

    // bias + bf16 round into LDS (layout depends on z), then coalesced store
    if (z < 2) {
        // Es[tok][c]
#pragma unroll
        for (int f = 0; f < 4; ++f) {
            const float bb = bias[c0 + f * 16 + l15] * bscale;
#pragma unroll
            for (int r = 0; r < 4; ++r)
                Es[(w * 16 + quad * 4 + r) * 68 + f * 16 + l15] = bf16rne(acc[f][r] + bb);
        }
    } else {
        // Es[c][tok]
#pragma unroll
        for (int f = 0; f < 4; ++f) {
            const float bb = bias[c0 + f * 16 + l15];
#pragma unroll
            for (int r = 0; r < 4; ++r)
                Es[(f * 16 + l15) * 68 + w * 16 + quad * 4 + r] = bf16rne(acc[f][r] + bb);
        }
    }
    __syncthreads();

    const int erow = tid >> 2;            // 0..63
    const int ecol = (tid & 3) * 16;      // 0,16,32,48 (+8 second store)
    uint4 pk0 = *(uint4*)&Es[erow * 68 + ecol];
    uint4 pk1 = *(uint4*)&Es[erow * 68 + ecol + 8];
    if (z < 2) {
        ushort_t* out = z ? Kb : Qb;
        ushort_t* p = &out[(size_t)(n0 + erow) * PROJ + c0 + ecol];
        *(uint4*)p = pk0;
        *(uint4*)(p + 8) = pk1;
    } else {
        ushort_t* p = &Vt[(size_t)(c0 + erow) * N_TOK + n0 + ecol];
        *(uint4*)p = pk0;
        *(uint4*)(p + 8) = pk1;
    }
}

// ---------------------------------------------------------------------------
// Kernel 2: fused sigmoid attention with bf16 MFMA (16x16x32),
// software-pipelined K/V staging (prefetch next tile's uint4s into registers
// during compute; global latency overlaps the MFMA/sigmoid phase).
// grid (N/64, HEADS, 2 key-splits), block 256 (wave w owns 16 queries).
// Scores arrive pre-scaled: t = -log2e*(q.k) -> p = rcpf(1 + exp2f(t)).
// P -> bf16 ties-away round (+0x8000) + v_perm pack.
// DEN via MFMA against a ones-B fragment.  LDS XOR-swizzled, conflict-free.
// ---------------------------------------------------------------------------
__global__ __launch_bounds__(256, 4) void attn_kernel(
    const ushort_t* __restrict__ Qb, const ushort_t* __restrict__ Kb,
    const ushort_t* __restrict__ Vt,
    float* __restrict__ NUM, float* __restrict__ DEN)
{
    const int h = blockIdx.y;
    const int z = blockIdx.z;
    const int n0 = blockIdx.x * 64;
    const int tid = threadIdx.x;
    const int w = tid >> 6;
    const int lane = tid & 63;
    const int l15 = lane & 15;
    const int quad = lane >> 4;

    __shared__ ushort_t Ks[64 * 64];      // [l][d] bf16, xor-swizzled chunks
    __shared__ ushort_t Vs[64 * 64];      // [d][l] bf16, xor-swizzled chunks
    __shared__ ushort_t Ps[4][16 * 72];   // per-wave [q][l] bf16 (144B rows)

    // Q B-fragments, register-resident (pre-scaled by -log2e).
    bf16x8 qb[2];
    {
        const ushort_t* base = Qb + (size_t)(n0 + w * 16 + l15) * PROJ + h * 64 + quad * 8;
        qb[0] = *(const bf16x8*)(base);
        qb[1] = *(const bf16x8*)(base + 32);
    }

    bf16x8 onesv;
#pragma unroll
    for (int j = 0; j < 8; ++j) onesv[j] = (__bf16)1.0f;

    f32x4 o[4] = {{0.f, 0.f, 0.f, 0.f}, {0.f, 0.f, 0.f, 0.f},
                  {0.f, 0.f, 0.f, 0.f}, {0.f, 0.f, 0.f, 0.f}};
    f32x4 dacc = {0.f, 0.f, 0.f, 0.f};

    // staging geometry: thread -> (row, 2 consecutive chunks), xor-swizzled
    const int srow = tid >> 2;
    const int sc2 = (tid & 3) * 2;
    const int sp0 = (sc2 ^ (srow & 7)) * 8;
    const int sp1 = ((sc2 + 1) ^ (srow & 7)) * 8;
    // read swizzle: frag row = f*16 + l15 -> mask = l15&7 (per-lane const)
    const int xm = l15 & 7;
    const int rofA = (quad ^ xm) * 8;
    const int rofB = ((4 + quad) ^ xm) * 8;

    const ushort_t* kgp = Kb + (size_t)h * 64 + sc2 * 8 +
                          (size_t)(z * 2048 + srow) * PROJ;
    const ushort_t* vgp = Vt + (size_t)h * 64 * N_TOK + (size_t)srow * N_TOK +
                          sc2 * 8 + z * 2048;

    // prefetch tile 0
    uint4 kr0 = ((const uint4*)kgp)[0], kr1 = ((const uint4*)kgp)[1];
    uint4 vr0 = ((const uint4*)vgp)[0], vr1 = ((const uint4*)vgp)[1];

    for (int lt = 0; lt < 32; ++lt) {
        __syncthreads();              // previous compute done reading LDS
        *(uint4*)&Ks[srow * 64 + sp0] = kr0;
        *(uint4*)&Ks[srow * 64 + sp1] = kr1;
        *(uint4*)&Vs[srow * 64 + sp0] = vr0;
        *(uint4*)&Vs[srow * 64 + sp1] = vr1;
        __syncthreads();              // staging visible

        if (lt < 31) {                // prefetch next tile during compute
            kgp += 64 * PROJ;
            vgp += 64;
            kr0 = ((const uint4*)kgp)[0]; kr1 = ((const uint4*)kgp)[1];
            vr0 = ((const uint4*)vgp)[0]; vr1 = ((const uint4*)vgp)[1];
        }

        // phase 1: T = -log2e * K.Q^T  (D[l][q])
        f32x4 s[4] = {{0.f, 0.f, 0.f, 0.f}, {0.f, 0.f, 0.f, 0.f},
                      {0.f, 0.f, 0.f, 0.f}, {0.f, 0.f, 0.f, 0.f}};
#pragma unroll
        for (int f = 0; f < 4; ++f) {
            bf16x8 ka = *(const bf16x8*)&Ks[(f * 16 + l15) * 64 + rofA];
            s[f] = __builtin_amdgcn_mfma_f32_16x16x32_bf16(ka, qb[0], s[f], 0, 0, 0);
        }
#pragma unroll
        for (int f = 0; f < 4; ++f) {
            bf16x8 ka = *(const bf16x8*)&Ks[(f * 16 + l15) * 64 + rofB];
            s[f] = __builtin_amdgcn_mfma_f32_16x16x32_bf16(ka, qb[1], s[f], 0, 0, 0);
        }

        // sigmoid = rcp(1 + 2^t); bf16 ties-away round; v_perm pack
        ushort_t* pw = &Ps[w][l15 * 72];
#pragma unroll
        for (int f = 0; f < 4; ++f) {
            float p0 = __builtin_amdgcn_rcpf(1.0f + __builtin_amdgcn_exp2f(s[f][0]));
            float p1 = __builtin_amdgcn_rcpf(1.0f + __builtin_amdgcn_exp2f(s[f][1]));
            float p2 = __builtin_amdgcn_rcpf(1.0f + __builtin_amdgcn_exp2f(s[f][2]));
            float p3 = __builtin_amdgcn_rcpf(1.0f + __builtin_amdgcn_exp2f(s[f][3]));
            unsigned u0 = __float_as_uint(p0) + 0x8000u;
            unsigned u1 = __float_as_uint(p1) + 0x8000u;
            unsigned u2 = __float_as_uint(p2) + 0x8000u;
            unsigned u3 = __float_as_uint(p3) + 0x8000u;
            uint2 pk;
            pk.x = __builtin_amdgcn_perm(u1, u0, 0x07060302u);
            pk.y = __builtin_amdgcn_perm(u3, u2, 0x07060302u);
            *(uint2*)&pw[f * 16 + quad * 4] = pk;
        }

        // phase 2: O += P.V ; DEN += P.1  (A = Ps rows, B = Vs rows / ones)
#pragma unroll
        for (int c = 0; c < 2; ++c) {
            bf16x8 pa = *(const bf16x8*)&Ps[w][l15 * 72 + c * 32 + quad * 8];
            const int rof = c ? rofB : rofA;
#pragma unroll
            for (int f = 0; f < 4; ++f) {
                bf16x8 vb = *(const bf16x8*)&Vs[(f * 16 + l15) * 64 + rof];
                o[f] = __builtin_amdgcn_mfma_f32_16x16x32_bf16(pa, vb, o[f], 0, 0, 0);
            }
            dacc = __builtin_amdgcn_mfma_f32_16x16x32_bf16(pa, onesv, dacc, 0, 0, 0);
        }
    }

    // epilogue: unnormalized numerator
#pragma unroll
    for (int f = 0; f < 4; ++f) {
#pragma unroll
        for (int r = 0; r < 4; ++r) {
            const int q = n0 + w * 16 + quad * 4 + r;
            NUM[((size_t)z * N_TOK + q) * PROJ + h * 64 + f * 16 + l15] = o[f][r];
        }
    }
    // DEN: dacc rows are q = quad*4+r, identical across cols; col 0 writes.
    if (l15 == 0) {
#pragma unroll
        for (int r = 0; r < 4; ++r)
            DEN[((size_t)z * N_TOK + n0 + w * 16 + quad * 4 + r) * HEADS + h] = dacc[r];
    }
}

// ---------------------------------------------------------------------------
// Kernel 3: out[n][d] = (1/8) * sum_h (NUM0+NUM1)/(DEN0+DEN1)
// ---------------------------------------------------------------------------
__global__ __launch_bounds__(256) void reduce_kernel(
    const float* __restrict__ NUM, const float* __restrict__ DEN,
    float* __restrict__ out)
{
    const int g = blockIdx.x * 256 + threadIdx.x;
    const int n = g >> 6;
    const int d = g & 63;
    float acc = 0.0f;
#pragma unroll
    for (int hh = 0; hh < HEADS; ++hh) {
        float num = NUM[(size_t)n * PROJ + hh * 64 + d] +
                    NUM[((size_t)N_TOK + n) * PROJ + hh * 64 + d];
        float dd = DEN[(size_t)n * HEADS + hh] +
                   DEN[((size_t)N_TOK + n) * HEADS + hh];
        acc += num / dd;
    }
    out[g] = acc * 0.125f;
}

extern "C" void kernel_launch(void* const* d_in, const int* in_sizes, int n_in,
                              void* d_out, int out_size, void* d_ws, size_t ws_size,
                              hipStream_t stream) {
    (void)in_sizes; (void)n_in; (void)out_size; (void)ws_size;
    const float* X  = (const float*)d_in[0];
    const float* Wq = (const float*)d_in[1];
    const float* bq = (const float*)d_in[2];
    const float* Wk = (const float*)d_in[3];
    const float* bk = (const float*)d_in[4];
    const float* Wv = (const float*)d_in[5];
    const float* bv = (const float*)d_in[6];
    float* out = (float*)d_out;

    // ws layout (~35.3 MB total):
    float* NUM = (float*)d_ws;                              // [2][N][PROJ] f32
    float* DEN = NUM + (size_t)2 * N_TOK * PROJ;            // [2][N][HEADS] f32
    ushort_t* Qb = (ushort_t*)(DEN + (size_t)2 * N_TOK * HEADS);
    ushort_t* Kb = Qb + (size_t)N_TOK * PROJ;
    ushort_t* Vt = Kb + (size_t)N_TOK * PROJ;               // [H][64][N]
    ushort_t* Xa = Vt + (size_t)N_TOK * PROJ;               // frag-packed X
    ushort_t* Wp = Xa + (size_t)N_TOK * IN_CH;              // frag-packed W x3

    cast_pack_kernel<<<dim3(704), 256, 0, stream>>>(X, Wq, Wk, Wv, Xa, Wp);
    proj_mfma_kernel<<<dim3(PROJ / 64, N_TOK / 64, 3), 256, 0, stream>>>(
        Xa, Wp, bq, bk, bv, Qb, Kb, Vt);
    attn_kernel<<<dim3(N_TOK / 64, HEADS, 2), 256, 0, stream>>>(
        Qb, Kb, Vt, NUM, DEN);
    reduce_kernel<<<dim3(N_TOK * OUT_CH / 256), 256, 0, stream>>>(NUM, DEN, out);
}